// Round 8
// baseline (86.616 us; speedup 1.0000x reference)
//
#include <hip/hip_runtime.h>

#define H_IN 4096
#define W_IN 4096
#define KH 15
#define KW 15
#define OH (H_IN - KH + 1)   // 4082
#define OW (W_IN - KW + 1)   // 4082

#define NJ 4                        // 16-col j-frags per wave
#define WROWS 16                    // output rows per wave-tile
#define WCOLS (16 * NJ)             // 64 output cols per wave-tile
#define SROWS (WROWS + KH - 1)      // 30 staged rows
#define SCH 10                      // 16B chunks per staged row (80 bf16 cols)
#define ROW_USH 88                  // stride = 11 granules (odd): A-read bank-group
                                    // (3*(l&15)+(l>>4))%8 -> exactly 2 lanes/group
                                    // per quarter-wave (2-way = free, m136)
#define WAVE_USH (SROWS * ROW_USH)  // 2640 ushort = 5280 B per wave
#define TPW 4                       // y-tiles per wave (block walks a 16-row band)

typedef __attribute__((ext_vector_type(8))) short short8;   // MFMA A/B frag
typedef __attribute__((ext_vector_type(4))) float f32x4;    // MFMA C/D frag

__device__ __forceinline__ ushort f2bf(float f) {
    union { float f; uint32_t u; } v; v.f = f;
    uint32_t r = (v.u + 0x7FFFu + ((v.u >> 16) & 1u)) >> 16;  // RNE
    return (ushort)r;
}
__device__ __forceinline__ uint32_t pk2(float a, float b) {
    return (uint32_t)f2bf(a) | ((uint32_t)f2bf(b) << 16);
}

__global__ __launch_bounds__(256, 4)
void conv2d_mfma_wavetile(const float* __restrict__ X,
                          const float* __restrict__ Wt,
                          const float* __restrict__ Bias,
                          float* __restrict__ Out)
{
    __shared__ ushort s_w[KH * 64 * 8];      // 15360 B, persistent weight frags
    __shared__ ushort s_x[4 * WAVE_USH];     // 21120 B, 4 wave-private tiles

    const int tid = threadIdx.x;
    const int l = tid & 63;
    const int w = tid >> 6;

    // ---- build banded Toeplitz weight frags once (persistent region) ----
    // B[k][j] = w[kh][k-j]; lane l holds B[8*(l>>4)+u][l&15], u=0..7
    for (int idx = tid; idx < KH * 64; idx += 256) {
        int kh = idx >> 6, ll = idx & 63;
        int j = ll & 15, k0 = (ll >> 4) * 8;
        ushort* dst = &s_w[idx * 8];
#pragma unroll
        for (int u = 0; u < 8; ++u) {
            int kw = k0 + u - j;
            dst[u] = f2bf((kw >= 0 && kw < KW) ? Wt[kh * KW + kw] : 0.0f);
        }
    }
    __syncthreads();    // only block-wide barrier in the kernel

    ushort* const my = &s_x[w * WAVE_USH];
    const ushort* const abase = my + (l & 15) * ROW_USH + (l >> 4) * 8;
    const ushort* const bbase = &s_w[l * 8];
    const float b = Bias[0];

    // ---- wave -> tile mapping: 4 waves of a block SIDE-BY-SIDE in x ----
    // block covers a 16-row x 256-col output band -> 1KB contiguous rows,
    // written concurrently -> full-line L2 merging (write-amp fix)
    const int tx  = blockIdx.x * 4 + w;     // x tile, 0..63
    const int ox0 = tx * WCOLS;
    const bool xint = (ox0 + SCH * 8 <= W_IN);

#pragma unroll 1
    for (int t = 0; t < TPW; ++t) {
        const int ty  = blockIdx.y * TPW + t;   // y tile, 0..255
        const int iy0 = ty * WROWS;

        // ---- wave-private stage: 30 rows x 80 cols fp32 -> bf16 ----
#pragma unroll
        for (int it = 0; it < 5; ++it) {
            int idx = it * 64 + l;
            if (idx < SROWS * SCH) {
                int r = idx / SCH, q = idx % SCH;
                int gy = min(iy0 + r, H_IN - 1);
                const float* rp = X + (size_t)gy * W_IN;
                int gx = ox0 + q * 8;
                float4 va, vb;
                if (xint) {
                    va = *reinterpret_cast<const float4*>(rp + gx);
                    vb = *reinterpret_cast<const float4*>(rp + gx + 4);
                } else {
                    va.x = rp[min(gx + 0, W_IN - 1)];
                    va.y = rp[min(gx + 1, W_IN - 1)];
                    va.z = rp[min(gx + 2, W_IN - 1)];
                    va.w = rp[min(gx + 3, W_IN - 1)];
                    vb.x = rp[min(gx + 4, W_IN - 1)];
                    vb.y = rp[min(gx + 5, W_IN - 1)];
                    vb.z = rp[min(gx + 6, W_IN - 1)];
                    vb.w = rp[min(gx + 7, W_IN - 1)];
                }
                uint4 pk;
                pk.x = pk2(va.x, va.y);
                pk.y = pk2(va.z, va.w);
                pk.z = pk2(vb.x, vb.y);
                pk.w = pk2(vb.z, vb.w);
                *reinterpret_cast<uint4*>(&my[r * ROW_USH + q * 8]) = pk;
            }
        }
        // no barrier: region is wave-private, per-wave DS ordering suffices

        // ---- compute: per kh {1 B-read, 4 A-reads, 4 MFMAs} ----
        f32x4 acc[NJ];
#pragma unroll
        for (int j = 0; j < NJ; ++j) acc[j] = (f32x4){0.f, 0.f, 0.f, 0.f};

#pragma unroll
        for (int kh = 0; kh < KH; ++kh) {
            short8 bf = *reinterpret_cast<const short8*>(bbase + kh * 64 * 8);
#pragma unroll
            for (int j = 0; j < NJ; ++j) {
                short8 a = *reinterpret_cast<const short8*>(abase + kh * ROW_USH + j * 16);
                acc[j] = __builtin_amdgcn_mfma_f32_16x16x32_bf16(a, bf, acc[j], 0, 0, 0);
            }
        }

        // ---- store: C/D layout col=lane&15, row=(lane>>4)*4+r ----
        const int orow0 = iy0 + (l >> 4) * 4;
        const int ocol  = ox0 + (l & 15);
        if (iy0 + WROWS <= OH && ox0 + WCOLS <= OW) {
            float* op0 = &Out[(size_t)orow0 * OW + ocol];
#pragma unroll
            for (int j = 0; j < NJ; ++j) {
#pragma unroll
                for (int r = 0; r < 4; ++r)
                    op0[(size_t)r * OW + j * 16] = acc[j][r] + b;
            }
        } else {
#pragma unroll
            for (int j = 0; j < NJ; ++j) {
                int oc = ocol + j * 16;
                if (oc < OW) {
#pragma unroll
                    for (int r = 0; r < 4; ++r) {
                        int orow = orow0 + r;
                        if (orow < OH)
                            Out[(size_t)orow * OW + oc] = acc[j][r] + b;
                    }
                }
            }
        }
    }
}

extern "C" void kernel_launch(void* const* d_in, const int* in_sizes, int n_in,
                              void* d_out, int out_size, void* d_ws, size_t ws_size,
                              hipStream_t stream)
{
    const float* X    = (const float*)d_in[0];
    const float* Wt   = (const float*)d_in[1];
    const float* Bias = (const float*)d_in[2];
    float* Out        = (float*)d_out;

    // x fastest: adjacent-x blocks co-dispatched -> boundary lines merge in L2
    dim3 grid(16, 64);   // 16 x-blocks (4 waves wide) x 64 y-groups (TPW=4)
    dim3 block(256);
    hipLaunchKernelGGL(conv2d_mfma_wavetile, grid, block, 0, stream, X, Wt, Bias, Out);
}

// Round 9
// 51.887 us; speedup vs baseline: 1.6693x; 1.6693x over previous
//
#include <hip/hip_runtime.h>
#include <hip/hip_bf16.h>

#define H_IN 4096
#define W_IN 4096
#define KH 15
#define KW 15
#define OH (H_IN - KH + 1)   // 4082
#define OW (W_IN - KW + 1)   // 4082

#define BM 64                // output rows per block (4 waves x 16)
#define BN 128               // output cols per block (NJ=8 j-frags)
#define NJ (BN / 16)         // 8
#define SROWS (BM + KH - 1)  // 78 staged rows
#define SCOLS 144            // staged bf16 cols (128 + 16 k-window)
#define SSTR  152            // LDS row stride in ushort = 19 granules (19%8==3):
                             // A-read bank-group (3*(l&15) + (l>>4) + 2j) % 8 is
                             // uniform at 16/32/64-lane granularity (2/4/8 per group)
#define SCH4 36              // float4 chunks per staged row
#define STAGE_N (SROWS * SCH4)   // 2808 items

typedef __attribute__((ext_vector_type(8))) short short8;   // MFMA A/B frag
typedef __attribute__((ext_vector_type(4))) float f32x4;    // MFMA C/D frag

__device__ __forceinline__ ushort f2bf(float f) {
    __hip_bfloat16 h = __float2bfloat16(f);       // native v_cvt path (m240)
    return __builtin_bit_cast(ushort, h);
}

__global__ __launch_bounds__(256, 2)
void conv2d_mfma_bf16(const float* __restrict__ X,
                      const float* __restrict__ Wt,
                      const float* __restrict__ Bias,
                      float* __restrict__ Out)
{
    __shared__ ushort s_w[KH * 64 * 8];      // 15360 B banded weight frags (persistent)
    __shared__ ushort s_x[SROWS * SSTR];     // 23712 B input tile (bf16)

    const int tid = threadIdx.x;
    const int l = tid & 63;
    const int w = tid >> 6;
    const int ox0 = blockIdx.x * BN;
    const int oy0 = blockIdx.y * BM;

    // ---- banded Toeplitz weight frags: B[k][j] = w[kh][k-j] ----
    // lane l holds B[8*(l>>4)+u][l&15], u=0..7
    for (int idx = tid; idx < KH * 64; idx += 256) {
        int kh = idx >> 6, ll = idx & 63;
        int j = ll & 15, k0 = (ll >> 4) * 8;
        ushort* dst = &s_w[idx * 8];
#pragma unroll
        for (int u = 0; u < 8; ++u) {
            int kw = k0 + u - j;
            dst[u] = f2bf((kw >= 0 && kw < KW) ? Wt[kh * KW + kw] : 0.0f);
        }
    }

    // ---- stage X tile (fp32 -> bf16), clamped at edges ----
    const bool xint = (ox0 + SCOLS <= W_IN);
    for (int i = tid; i < STAGE_N; i += 256) {
        int r  = i / SCH4;
        int c4 = i % SCH4;
        int gy = min(oy0 + r, H_IN - 1);
        const float* rp = X + (size_t)gy * W_IN;
        int gx = ox0 + c4 * 4;
        float4 v;
        if (xint) {
            v = *reinterpret_cast<const float4*>(rp + gx);
        } else {
            v.x = rp[min(gx + 0, W_IN - 1)];
            v.y = rp[min(gx + 1, W_IN - 1)];
            v.z = rp[min(gx + 2, W_IN - 1)];
            v.w = rp[min(gx + 3, W_IN - 1)];
        }
        uint2 pk;
        pk.x = (uint32_t)f2bf(v.x) | ((uint32_t)f2bf(v.y) << 16);
        pk.y = (uint32_t)f2bf(v.z) | ((uint32_t)f2bf(v.w) << 16);
        *reinterpret_cast<uint2*>(&s_x[r * SSTR + c4 * 4]) = pk;
    }
    __syncthreads();

    // ---- compute: per kh {1 B-read, 8 A-reads, 8 MFMAs} ----
    const ushort* const abase = &s_x[(w * 16 + (l & 15)) * SSTR + (l >> 4) * 8];
    const ushort* const bbase = &s_w[l * 8];

    f32x4 acc[NJ];
#pragma unroll
    for (int j = 0; j < NJ; ++j) acc[j] = (f32x4){0.f, 0.f, 0.f, 0.f};

#pragma unroll
    for (int kh = 0; kh < KH; ++kh) {
        short8 bf = *reinterpret_cast<const short8*>(bbase + kh * 64 * 8);
        const ushort* arow = abase + kh * SSTR;
#pragma unroll
        for (int j = 0; j < NJ; ++j) {
            short8 a = *reinterpret_cast<const short8*>(arow + j * 16);
            acc[j] = __builtin_amdgcn_mfma_f32_16x16x32_bf16(a, bf, acc[j], 0, 0, 0);
        }
    }

    // ---- store: C/D layout col=lane&15, row=(lane>>4)*4+r ----
    const float b = Bias[0];
    const int orow0 = oy0 + w * 16 + (l >> 4) * 4;
    const int ocol  = ox0 + (l & 15);
    if (oy0 + BM <= OH && ox0 + BN <= OW) {
        float* op0 = &Out[(size_t)orow0 * OW + ocol];
#pragma unroll
        for (int j = 0; j < NJ; ++j) {
#pragma unroll
            for (int r = 0; r < 4; ++r)
                op0[(size_t)r * OW + j * 16] = acc[j][r] + b;
        }
    } else {
#pragma unroll
        for (int j = 0; j < NJ; ++j) {
            int oc = ocol + j * 16;
            if (oc < OW) {
#pragma unroll
                for (int r = 0; r < 4; ++r) {
                    int orow = orow0 + r;
                    if (orow < OH)
                        Out[(size_t)orow * OW + oc] = acc[j][r] + b;
                }
            }
        }
    }
}

extern "C" void kernel_launch(void* const* d_in, const int* in_sizes, int n_in,
                              void* d_out, int out_size, void* d_ws, size_t ws_size,
                              hipStream_t stream)
{
    const float* X    = (const float*)d_in[0];
    const float* Wt   = (const float*)d_in[1];
    const float* Bias = (const float*)d_in[2];
    float* Out        = (float*)d_out;

    dim3 grid((OW + BN - 1) / BN,    // 32
              (OH + BM - 1) / BM);   // 64
    dim3 block(256);
    hipLaunchKernelGGL(conv2d_mfma_bf16, grid, block, 0, stream, X, Wt, Bias, Out);
}

// Round 10
// 51.522 us; speedup vs baseline: 1.6812x; 1.0071x over previous
//
#include <hip/hip_runtime.h>
#include <hip/hip_bf16.h>

#define H_IN 4096
#define W_IN 4096
#define KH 15
#define KW 15
#define OH (H_IN - KH + 1)   // 4082
#define OW (W_IN - KW + 1)   // 4082

#define BM 64                // output rows per block (4 waves x 16)
#define BN 128               // output cols per block (NJ=8 j-frags)
#define NJ (BN / 16)         // 8
#define SROWS (BM + KH - 1)  // 78 staged rows
#define SCOLS 144            // staged bf16 cols (128 + 16 k-window)
#define SSTR  152            // LDS row stride in ushort = 19 granules (19%8==3):
                             // A-read bank-group (3*(l&15)+(l>>4)+2j)%8 uniform at
                             // 16/32/64-lane service granularity (2/4/8 per group)
#define SCH4 36              // float4 chunks per staged row
#define STAGE_N (SROWS * SCH4)   // 2808 items

typedef __attribute__((ext_vector_type(8))) short short8;   // MFMA A/B frag
typedef __attribute__((ext_vector_type(4))) float f32x4;    // MFMA C/D frag

__device__ __forceinline__ ushort f2bf(float f) {
    __hip_bfloat16 h = __float2bfloat16(f);       // native v_cvt path
    return __builtin_bit_cast(ushort, h);
}

// ---- prep: build banded Toeplitz weight frags into workspace (15 KB) ----
// B[k][j] = w[kh][k-j]; frag layout: lane l holds B[8*(l>>4)+u][l&15], u=0..7
__global__ __launch_bounds__(256)
void build_wfrags(const float* __restrict__ Wt, ushort* __restrict__ Bw)
{
    int idx = blockIdx.x * 256 + threadIdx.x;    // frag-lane index
    if (idx < KH * 64) {
        int kh = idx >> 6, l = idx & 63;
        int j = l & 15, k0 = (l >> 4) * 8;
        union { ushort u[8]; uint4 v; } t;
#pragma unroll
        for (int u = 0; u < 8; ++u) {
            int kw = k0 + u - j;
            t.u[u] = f2bf((kw >= 0 && kw < KW) ? Wt[kh * KW + kw] : 0.0f);
        }
        *reinterpret_cast<uint4*>(&Bw[idx * 8]) = t.v;   // single 16B store
    }
}

__global__ __launch_bounds__(256, 5)
void conv2d_mfma_bf16(const float* __restrict__ X,
                      const ushort* __restrict__ Bw,
                      const float* __restrict__ Bias,
                      float* __restrict__ Out)
{
    __shared__ ushort s_x[SROWS * SSTR];     // 23712 B — tile only

    const int tid = threadIdx.x;
    const int l = tid & 63;
    const int w = tid >> 6;
    const int ox0 = blockIdx.x * BN;
    const int oy0 = blockIdx.y * BM;

    // ---- stage X tile (fp32 -> bf16), clamped at edges ----
    const bool xint = (ox0 + SCOLS <= W_IN);
    for (int i = tid; i < STAGE_N; i += 256) {
        int r  = i / SCH4;
        int c4 = i % SCH4;
        int gy = min(oy0 + r, H_IN - 1);
        const float* rp = X + (size_t)gy * W_IN;
        int gx = ox0 + c4 * 4;
        float4 v;
        if (xint) {
            v = *reinterpret_cast<const float4*>(rp + gx);
        } else {
            v.x = rp[min(gx + 0, W_IN - 1)];
            v.y = rp[min(gx + 1, W_IN - 1)];
            v.z = rp[min(gx + 2, W_IN - 1)];
            v.w = rp[min(gx + 3, W_IN - 1)];
        }
        uint2 pk;
        pk.x = (uint32_t)f2bf(v.x) | ((uint32_t)f2bf(v.y) << 16);
        pk.y = (uint32_t)f2bf(v.z) | ((uint32_t)f2bf(v.w) << 16);
        *reinterpret_cast<uint2*>(&s_x[r * SSTR + c4 * 4]) = pk;
    }
    __syncthreads();       // only barrier in the kernel

    // ---- compute: per kh {1 B-load (global, L1-hot), 8 A-reads, 8 MFMAs} ----
    const ushort* const abase = &s_x[(w * 16 + (l & 15)) * SSTR + (l >> 4) * 8];
    const ushort* const bbase = Bw + l * 8;

    f32x4 acc[NJ];
#pragma unroll
    for (int j = 0; j < NJ; ++j) acc[j] = (f32x4){0.f, 0.f, 0.f, 0.f};

#pragma unroll
    for (int kh = 0; kh < KH; ++kh) {
        short8 bf = *reinterpret_cast<const short8*>(bbase + kh * 64 * 8);
        const ushort* arow = abase + kh * SSTR;
#pragma unroll
        for (int j = 0; j < NJ; ++j) {
            short8 a = *reinterpret_cast<const short8*>(arow + j * 16);
            acc[j] = __builtin_amdgcn_mfma_f32_16x16x32_bf16(a, bf, acc[j], 0, 0, 0);
        }
    }

    // ---- store: C/D layout col=lane&15, row=(lane>>4)*4+r ----
    const float b = Bias[0];
    const int orow0 = oy0 + w * 16 + (l >> 4) * 4;
    const int ocol  = ox0 + (l & 15);
    if (oy0 + BM <= OH && ox0 + BN <= OW) {
        float* op0 = &Out[(size_t)orow0 * OW + ocol];
#pragma unroll
        for (int j = 0; j < NJ; ++j) {
#pragma unroll
            for (int r = 0; r < 4; ++r)
                op0[(size_t)r * OW + j * 16] = acc[j][r] + b;
        }
    } else {
#pragma unroll
        for (int j = 0; j < NJ; ++j) {
            int oc = ocol + j * 16;
            if (oc < OW) {
#pragma unroll
                for (int r = 0; r < 4; ++r) {
                    int orow = orow0 + r;
                    if (orow < OH)
                        Out[(size_t)orow * OW + oc] = acc[j][r] + b;
                }
            }
        }
    }
}

extern "C" void kernel_launch(void* const* d_in, const int* in_sizes, int n_in,
                              void* d_out, int out_size, void* d_ws, size_t ws_size,
                              hipStream_t stream)
{
    const float* X    = (const float*)d_in[0];
    const float* Wt   = (const float*)d_in[1];
    const float* Bias = (const float*)d_in[2];
    float* Out        = (float*)d_out;
    ushort* Bw        = (ushort*)d_ws;        // 15*64*8 ushort = 15360 B

    // prep: build weight frags (deterministic, every call)
    hipLaunchKernelGGL(build_wfrags, dim3((KH * 64 + 255) / 256), dim3(256), 0, stream,
                       Wt, Bw);

    dim3 grid((OW + BN - 1) / BN,    // 32
              (OH + BM - 1) / BM);   // 64
    dim3 block(256);
    hipLaunchKernelGGL(conv2d_mfma_bf16, grid, block, 0, stream, X, Bw, Bias, Out);
}

// Round 11
// 43.624 us; speedup vs baseline: 1.9855x; 1.1810x over previous
//
#include <hip/hip_runtime.h>
#include <hip/hip_bf16.h>

#define H_IN 4096
#define W_IN 4096
#define KH 15
#define KW 15
#define OH (H_IN - KH + 1)   // 4082
#define OW (W_IN - KW + 1)   // 4082

#define BM 64                // output rows per block (4 waves x 16)
#define BN 128               // output cols per block (NJ=8 j-frags)
#define NJ (BN / 16)         // 8
#define SROWS (BM + KH - 1)  // 78 staged rows
#define SCOLS 144            // staged bf16 cols (128 + 16 k-window)
#define SSTR  152            // LDS row stride in ushort = 19 granules (19%8==3):
                             // A-read bank-group (3*(l&15)+(l>>4)+2j)%8 uniform at
                             // 16/32/64-lane service granularity (2/4/8 per group)
#define SCH4 36              // float4 chunks per staged row
#define STAGE_N (SROWS * SCH4)   // 2808 items
#define NLOAD 11             // ceil(STAGE_N / 256)

typedef __attribute__((ext_vector_type(8))) short short8;   // MFMA A/B frag
typedef __attribute__((ext_vector_type(4))) float f32x4;    // MFMA C/D frag

__device__ __forceinline__ ushort f2bf(float f) {
    __hip_bfloat16 h = __float2bfloat16(f);       // native v_cvt path
    return __builtin_bit_cast(ushort, h);
}

// ---- prep: build banded Toeplitz weight frags into workspace (15 KB) ----
// B[k][j] = w[kh][k-j]; frag layout: lane l holds B[8*(l>>4)+u][l&15], u=0..7
__global__ __launch_bounds__(256)
void build_wfrags(const float* __restrict__ Wt, ushort* __restrict__ Bw)
{
    int idx = blockIdx.x * 256 + threadIdx.x;    // frag-lane index
    if (idx < KH * 64) {
        int kh = idx >> 6, l = idx & 63;
        int j = l & 15, k0 = (l >> 4) * 8;
        union { ushort u[8]; uint4 v; } t;
#pragma unroll
        for (int u = 0; u < 8; ++u) {
            int kw = k0 + u - j;
            t.u[u] = f2bf((kw >= 0 && kw < KW) ? Wt[kh * KW + kw] : 0.0f);
        }
        *reinterpret_cast<uint4*>(&Bw[idx * 8]) = t.v;   // single 16B store
    }
}

__global__ __launch_bounds__(256, 4)
void conv2d_mfma_bf16(const float* __restrict__ X,
                      const ushort* __restrict__ Bw,
                      const float* __restrict__ Bias,
                      float* __restrict__ Out)
{
    __shared__ ushort s_x[SROWS * SSTR];     // 23712 B — tile only

    const int tid = threadIdx.x;
    const int l = tid & 63;
    const int w = tid >> 6;
    const int ox0 = blockIdx.x * BN;
    const int oy0 = blockIdx.y * BM;
    const bool xint = (ox0 + SCOLS <= W_IN);

    // ---- stage phase A: issue ALL tile loads (one vmcnt drain, T14 split) ----
    float4 v[NLOAD];
#pragma unroll
    for (int k = 0; k < NLOAD; ++k) {
        int i = tid + 256 * k;
        if (i < STAGE_N) {
            int r  = i / SCH4;
            int c4 = i % SCH4;
            int gy = min(oy0 + r, H_IN - 1);
            const float* rp = X + (size_t)gy * W_IN;
            int gx = ox0 + c4 * 4;
            if (xint) {
                v[k] = *reinterpret_cast<const float4*>(rp + gx);
            } else {
                v[k].x = rp[min(gx + 0, W_IN - 1)];
                v[k].y = rp[min(gx + 1, W_IN - 1)];
                v[k].z = rp[min(gx + 2, W_IN - 1)];
                v[k].w = rp[min(gx + 3, W_IN - 1)];
            }
        }
    }
    // ---- stage phase B: convert + LDS write ----
#pragma unroll
    for (int k = 0; k < NLOAD; ++k) {
        int i = tid + 256 * k;
        if (i < STAGE_N) {
            int r  = i / SCH4;
            int c4 = i % SCH4;
            uint2 pk;
            pk.x = (uint32_t)f2bf(v[k].x) | ((uint32_t)f2bf(v[k].y) << 16);
            pk.y = (uint32_t)f2bf(v[k].z) | ((uint32_t)f2bf(v[k].w) << 16);
            *reinterpret_cast<uint2*>(&s_x[r * SSTR + c4 * 4]) = pk;
        }
    }
    __syncthreads();       // only barrier in the kernel

    // ---- hoist all 15 B-frags in one burst (60 VGPR, L1-hot, coalesced) ----
    const ushort* const bbase = Bw + l * 8;
    short8 bfr[KH];
#pragma unroll
    for (int kh = 0; kh < KH; ++kh)
        bfr[kh] = *reinterpret_cast<const short8*>(bbase + kh * 64 * 8);
    __builtin_amdgcn_sched_barrier(0);   // pin: loads issued before kh loop

    // ---- compute: per kh {8 A-reads, 8 MFMAs} — no global access in loop ----
    const ushort* const abase = &s_x[(w * 16 + (l & 15)) * SSTR + (l >> 4) * 8];

    f32x4 acc[NJ];
#pragma unroll
    for (int j = 0; j < NJ; ++j) acc[j] = (f32x4){0.f, 0.f, 0.f, 0.f};

#pragma unroll
    for (int kh = 0; kh < KH; ++kh) {
        const ushort* arow = abase + kh * SSTR;
#pragma unroll
        for (int j = 0; j < NJ; ++j) {
            short8 a = *reinterpret_cast<const short8*>(arow + j * 16);
            acc[j] = __builtin_amdgcn_mfma_f32_16x16x32_bf16(a, bfr[kh], acc[j], 0, 0, 0);
        }
    }

    // ---- store: C/D layout col=lane&15, row=(lane>>4)*4+r ----
    const float b = Bias[0];
    const int orow0 = oy0 + w * 16 + (l >> 4) * 4;
    const int ocol  = ox0 + (l & 15);
    if (oy0 + BM <= OH && ox0 + BN <= OW) {
        float* op0 = &Out[(size_t)orow0 * OW + ocol];
#pragma unroll
        for (int j = 0; j < NJ; ++j) {
#pragma unroll
            for (int r = 0; r < 4; ++r)
                op0[(size_t)r * OW + j * 16] = acc[j][r] + b;
        }
    } else {
#pragma unroll
        for (int j = 0; j < NJ; ++j) {
            int oc = ocol + j * 16;
            if (oc < OW) {
#pragma unroll
                for (int r = 0; r < 4; ++r) {
                    int orow = orow0 + r;
                    if (orow < OH)
                        Out[(size_t)orow * OW + oc] = acc[j][r] + b;
                }
            }
        }
    }
}

extern "C" void kernel_launch(void* const* d_in, const int* in_sizes, int n_in,
                              void* d_out, int out_size, void* d_ws, size_t ws_size,
                              hipStream_t stream)
{
    const float* X    = (const float*)d_in[0];
    const float* Wt   = (const float*)d_in[1];
    const float* Bias = (const float*)d_in[2];
    float* Out        = (float*)d_out;
    ushort* Bw        = (ushort*)d_ws;        // 15*64*8 ushort = 15360 B

    // prep: build weight frags (deterministic, every call)
    hipLaunchKernelGGL(build_wfrags, dim3((KH * 64 + 255) / 256), dim3(256), 0, stream,
                       Wt, Bw);

    dim3 grid((OW + BN - 1) / BN,    // 32
              (OH + BM - 1) / BM);   // 64
    dim3 block(256);
    hipLaunchKernelGGL(conv2d_mfma_bf16, grid, block, 0, stream, X, Bw, Bias, Out);
}